// Round 13
// baseline (17.276 us; speedup 1.0000x reference)
//
#include <hip/hip_runtime.h>

#define L 4096
#define NT 256
#define C 16                  // elements per thread (one chunk per thread)
#define NC (NT + 4)           // chunk rows incl. 2 pads each side
#define SS 20                 // scan row stride in words (80B, 16B-aligned)
#define MAXIT 30000           // safety cap (never reached in practice)

typedef unsigned int u32;
typedef unsigned long long u64;

static __device__ __forceinline__ u32 umax(u32 a, u32 b) { return a > b ? a : b; }

// Complete all outstanding LDS ops before any later ones issue; compiler fence.
#define LDS_FENCE() asm volatile("s_waitcnt lgkmcnt(0)" ::: "memory")

// Recompute prefix/suffix scans + TA for my chunk, write to LDS; update run/om.
#define RESCAN()                                                          \
    do {                                                                  \
        u32* pr_ = &pfxS[cc * SS];                                        \
        u32* sr_ = &sfxS[cc * SS];                                        \
        u32 p_ = 0, nom_ = 0;                                             \
        _Pragma("unroll")                                                 \
        for (int g_ = 0; g_ < C; g_ += 4) {                               \
            u32 t0_, t1_, t2_, t3_, k_;                                   \
            k_ = key[g_+0]; if (k_ > p_) { p_ = k_; nom_ = g_+0; } t0_ = p_; \
            k_ = key[g_+1]; if (k_ > p_) { p_ = k_; nom_ = g_+1; } t1_ = p_; \
            k_ = key[g_+2]; if (k_ > p_) { p_ = k_; nom_ = g_+2; } t2_ = p_; \
            k_ = key[g_+3]; if (k_ > p_) { p_ = k_; nom_ = g_+3; } t3_ = p_; \
            *reinterpret_cast<uint4*>(pr_ + g_) = make_uint4(t0_,t1_,t2_,t3_); \
        }                                                                 \
        u32 s_ = 0;                                                       \
        _Pragma("unroll")                                                 \
        for (int g_ = C - 4; g_ >= 0; g_ -= 4) {                          \
            u32 t3_ = umax(s_, key[g_+3]);                                \
            u32 t2_ = umax(t3_, key[g_+2]);                               \
            u32 t1_ = umax(t2_, key[g_+1]);                               \
            u32 t0_ = umax(t1_, key[g_+0]);                               \
            *reinterpret_cast<uint4*>(sr_ + g_) = make_uint4(t0_,t1_,t2_,t3_); \
            s_ = t0_;                                                     \
        }                                                                 \
        TAc[cc] = p_;                                                     \
        run = p_; om = nom_;                                              \
    } while (0)

#define ZERO_SCANS()                                                      \
    do {                                                                  \
        uint4 z_ = make_uint4(0,0,0,0);                                   \
        u32* pr_ = &pfxS[cc * SS];                                        \
        u32* sr_ = &sfxS[cc * SS];                                        \
        _Pragma("unroll")                                                 \
        for (int q_ = 0; q_ < C; q_ += 4) {                               \
            *reinterpret_cast<uint4*>(pr_ + q_) = z_;                     \
            *reinterpret_cast<uint4*>(sr_ + q_) = z_;                     \
        }                                                                 \
        TAc[cc] = 0;                                                      \
    } while (0)

// suppressed(o) iff any winner bit within [o, o+64] of the 80-bit window
// space [base-32, base+47]: W0 = cc-2 | cc-1<<16 | (own=0) | cc+1<<48, W1 = cc+2.
#define SUPMASK_OF(mm0, mm1, mm3, mm4, dst)                               \
    do {                                                                  \
        u64 w0_ = (u64)(mm0) | ((u64)(mm1) << 16) | ((u64)(mm3) << 48);   \
        u32 w1_ = (mm4);                                                  \
        u32 sm_ = 0;                                                      \
        if (w0_) { int h_ = 63 - __clzll(w0_);                            \
                   sm_ = (h_ >= 15) ? 0xffffu : ((2u << h_) - 1u); }      \
        if (w1_) { int l_ = __ffs((int)w1_) - 1;                          \
                   sm_ |= ~((1u << l_) - 1u); }                           \
        (dst) = sm_ & 0xffffu;                                            \
    } while (0)

// One block per row; 4 waves free-running with NO barriers in the loop.
// Exact greedy NMS: monotone racy peeling. Keys/scans/TA only decrease and
// winC is cumulative write-once => stale reads only overstate blockers
// (delay, never corrupt). Commit protocol (re-read winC after scan reads,
// ordered by data dependency; publisher fences winC before zeroing scans)
// eliminates the vanished-winner race. Ties: left blocks on >=, right on >
// == stable argsort(-|x|) order of the reference.
__global__ __launch_bounds__(NT) void extrema_nms_kernel(const float* __restrict__ in,
                                                         float* __restrict__ out) {
    __shared__ u32 pfxS[NC * SS];
    __shared__ u32 sfxS[NC * SS];
    __shared__ u32 TAc[NC];
    __shared__ u32 winC[NC];     // cumulative winner mask, one-hot, write-once

    volatile u32* const vpfx = pfxS;
    volatile u32* const vsfx = sfxS;
    volatile u32* const vTA  = TAc;
    volatile u32* const vwin = winC;

    const int tid = threadIdx.x;
    const int cc = tid + 2;
    const int base = tid * C;
    const float* xrow = in + (size_t)blockIdx.x * L;

    // ---- pads (written once, never again) ----
    if (tid < 4 * SS) {
        int rsel = tid / SS;
        int row = (rsel & 1) + ((rsel >> 1) ? (NT + 2) : 0);
        int col = tid % SS;
        pfxS[row * SS + col] = 0;
        sfxS[row * SS + col] = 0;
    }
    if (tid < 4) {
        int slot = (tid & 1) + ((tid >> 1) ? (NT + 2) : 0);
        TAc[slot] = 0;
        winC[slot] = 0;
    }
    winC[cc] = 0;

    // ---- load own 16 x values + boundary neighbors ----
    float xv[C];
    #pragma unroll
    for (int k = 0; k < C; k += 4) {
        float4 f = *reinterpret_cast<const float4*>(xrow + base + k);
        xv[k] = f.x; xv[k + 1] = f.y; xv[k + 2] = f.z; xv[k + 3] = f.w;
    }
    float xl = (base > 0) ? xrow[base - 1] : 0.0f;
    float xr = (base + C < L) ? xrow[base + C] : 0.0f;

    // ---- extrema mask -> u32 keys ----
    // right[i] = (i<L-1) && x[i+1] >  x[i]; left[i] = (i==0) || x[i] <= x[i-1]
    u32 key[C];
    #pragma unroll
    for (int o = 0; o < C; ++o) {
        int i = base + o;
        float xi = xv[o];
        float xp = (o == 0) ? xl : xv[o - 1];
        float xn = (o == C - 1) ? xr : xv[o + 1];
        bool right = (i < L - 1) && (xn > xi);
        bool left  = (i == 0) || (xi <= xp);
        bool neg   = (xi <= 0.0f);
        bool ext = (right && left && neg) || (!right && !left && !neg);
        key[o] = ext ? ((__float_as_uint(xi) & 0x7fffffffu) + 1u) : 0u;
    }

    // ---- initial alive mask + scans ----
    u32 alivem = 0;
    #pragma unroll
    for (int o = 0; o < C; ++o) if (key[o]) alivem |= (1u << o);
    u32 run, om;
    RESCAN();
    u32 keptm = 0;
    __syncthreads();               // the only block barrier: init visibility

    // ---- barrier-free monotone peeling ----
    u64 appliedW0 = 0;
    u32 appliedW1 = 0;
    for (int it = 0; it < MAXIT; ++it) {
        if (__ballot(run != 0) == 0) break;    // wave-uniform exit
        if (run) {
            // batched reads: 4 winC + 4 scan scalars, one latency window
            u32 m0 = vwin[cc - 2], m1 = vwin[cc - 1];
            u32 m3 = vwin[cc + 1], m4 = vwin[cc + 2];
            u32 sL = vsfx[(cc - 2) * SS + (int)om];
            u32 tL = vTA[cc - 1], tR = vTA[cc + 1];
            u32 pR = vpfx[(cc + 2) * SS + (int)om];

            u64 W0 = (u64)m0 | ((u64)m1 << 16) | ((u64)m3 << 48);
            u32 W1 = m4;
            if (W0 != appliedW0 || W1 != appliedW1) {
                // ---- apply newly-seen winners ----
                appliedW0 = W0; appliedW1 = W1;
                u32 supmask; SUPMASK_OF(m0, m1, m3, m4, supmask);
                u32 nA = alivem & ~supmask;
                if (nA != alivem) {
                    alivem = nA;
                    if (nA == 0) {
                        ZERO_SCANS();
                        run = 0;
                        LDS_FENCE();
                    } else {
                        #pragma unroll
                        for (int o = 0; o < C; ++o)
                            key[o] = ((supmask >> o) & 1u) ? 0u : key[o];
                        RESCAN();
                        LDS_FENCE();           // publish fresh scans
                        // re-read scan operands at (possibly new) om
                        sL = vsfx[(cc - 2) * SS + (int)om];
                        tL = vTA[cc - 1]; tR = vTA[cc + 1];
                        pR = vpfx[(cc + 2) * SS + (int)om];
                    }
                }
            }
            // ---- detect: only the chunk's first argmax can win ----
            if (run) {
                u32 bL = umax(sL, tL);         // blocks iff >= run
                u32 bR = umax(tR, pR);         // blocks iff >  run
                if (bL < run && bR <= run) {
                    // commit protocol: fresh winC re-read AFTER scan reads
                    // (ordered by the bL/bR data dependency)
                    u32 n0 = vwin[cc - 2], n1 = vwin[cc - 1];
                    u32 n3 = vwin[cc + 1], n4 = vwin[cc + 2];
                    u32 sup2; SUPMASK_OF(n0, n1, n3, n4, sup2);
                    if (!((sup2 >> om) & 1u)) {
                        keptm |= 1u << om;
                        vwin[cc] = 1u << om;   // publish winner FIRST
                        LDS_FENCE();           // ...complete before zeroes issue
                        ZERO_SCANS();          // own chunk fully dies
                        run = 0; alivem = 0;
                        LDS_FENCE();
                    }
                    // else: new winner covers om; next iteration applies it
                }
            }
        }
    }

    // ---- output straight from registers (own region; no sync needed) ----
    float* orow = out + (size_t)blockIdx.x * L;
    #pragma unroll
    for (int k = 0; k < C; k += 4) {
        float4 f;
        f.x = ((keptm >> (k + 0)) & 1u) ? xv[k + 0] : 0.0f;
        f.y = ((keptm >> (k + 1)) & 1u) ? xv[k + 1] : 0.0f;
        f.z = ((keptm >> (k + 2)) & 1u) ? xv[k + 2] : 0.0f;
        f.w = ((keptm >> (k + 3)) & 1u) ? xv[k + 3] : 0.0f;
        *reinterpret_cast<float4*>(orow + base + k) = f;
    }
}

extern "C" void kernel_launch(void* const* d_in, const int* in_sizes, int n_in,
                              void* d_out, int out_size, void* d_ws, size_t ws_size,
                              hipStream_t stream) {
    const float* in = (const float*)d_in[0];
    float* out = (float*)d_out;
    int rows = in_sizes[0] / L;   // 128
    extrema_nms_kernel<<<rows, NT, 0, stream>>>(in, out);
}

// Round 14
// 13.925 us; speedup vs baseline: 1.2407x; 1.2407x over previous
//
#include <hip/hip_runtime.h>

#define L 4096
#define NT 256
#define C 16                  // elements per thread (one chunk per thread)
#define NC (NT + 4)           // chunk rows incl. 2 pads each side
#define SS 20                 // scan row stride in words (80B, 16B-aligned)
#define MAXIT 4000            // safety cap (never reached in practice)

typedef unsigned int u32;
typedef unsigned long long u64;

static __device__ __forceinline__ u32 umax(u32 a, u32 b) { return a > b ? a : b; }

// Compiler-only ordering fence: no instructions, just forbids reordering /
// caching of LDS accesses across it. Hardware DS ops complete in issue
// order per wave, which supplies the actual memory ordering.
#define CFENCE() asm volatile("" ::: "memory")

// Recompute prefix/suffix scans + TA for my chunk, write to LDS; update run/om.
#define RESCAN()                                                          \
    do {                                                                  \
        u32* pr_ = &pfxS[cc * SS];                                        \
        u32* sr_ = &sfxS[cc * SS];                                        \
        u32 p_ = 0, nom_ = 0;                                             \
        _Pragma("unroll")                                                 \
        for (int g_ = 0; g_ < C; g_ += 4) {                               \
            u32 t0_, t1_, t2_, t3_, k_;                                   \
            k_ = key[g_+0]; if (k_ > p_) { p_ = k_; nom_ = g_+0; } t0_ = p_; \
            k_ = key[g_+1]; if (k_ > p_) { p_ = k_; nom_ = g_+1; } t1_ = p_; \
            k_ = key[g_+2]; if (k_ > p_) { p_ = k_; nom_ = g_+2; } t2_ = p_; \
            k_ = key[g_+3]; if (k_ > p_) { p_ = k_; nom_ = g_+3; } t3_ = p_; \
            *reinterpret_cast<uint4*>(pr_ + g_) = make_uint4(t0_,t1_,t2_,t3_); \
        }                                                                 \
        u32 s_ = 0;                                                       \
        _Pragma("unroll")                                                 \
        for (int g_ = C - 4; g_ >= 0; g_ -= 4) {                          \
            u32 t3_ = umax(s_, key[g_+3]);                                \
            u32 t2_ = umax(t3_, key[g_+2]);                               \
            u32 t1_ = umax(t2_, key[g_+1]);                               \
            u32 t0_ = umax(t1_, key[g_+0]);                               \
            *reinterpret_cast<uint4*>(sr_ + g_) = make_uint4(t0_,t1_,t2_,t3_); \
            s_ = t0_;                                                     \
        }                                                                 \
        TAc[cc] = p_;                                                     \
        run = p_; om = nom_;                                              \
    } while (0)

#define ZERO_SCANS()                                                      \
    do {                                                                  \
        uint4 z_ = make_uint4(0,0,0,0);                                   \
        u32* pr_ = &pfxS[cc * SS];                                        \
        u32* sr_ = &sfxS[cc * SS];                                        \
        _Pragma("unroll")                                                 \
        for (int q_ = 0; q_ < C; q_ += 4) {                               \
            *reinterpret_cast<uint4*>(pr_ + q_) = z_;                     \
            *reinterpret_cast<uint4*>(sr_ + q_) = z_;                     \
        }                                                                 \
        TAc[cc] = 0;                                                      \
    } while (0)

// suppressed(o) iff any winner bit within [o, o+64] of the 80-bit window
// space [base-32, base+47]: W0 = cc-2 | cc-1<<16 | (own=0) | cc+1<<48, W1 = cc+2.
#define SUPMASK_OF(mm0, mm1, mm3, mm4, dst)                               \
    do {                                                                  \
        u64 w0_ = (u64)(mm0) | ((u64)(mm1) << 16) | ((u64)(mm3) << 48);   \
        u32 w1_ = (mm4);                                                  \
        u32 sm_ = 0;                                                      \
        if (w0_) { int h_ = 63 - __clzll(w0_);                            \
                   sm_ = (h_ >= 15) ? 0xffffu : ((2u << h_) - 1u); }      \
        if (w1_) { int l_ = __ffs((int)w1_) - 1;                          \
                   sm_ |= ~((1u << l_) - 1u); }                           \
        (dst) = sm_ & 0xffffu;                                            \
    } while (0)

// One block per row; 4 waves free-running with NO barriers in the loop.
// Exact greedy NMS: monotone racy peeling. Keys/scans/TA only decrease and
// winC is cumulative write-once one-hot => stale reads only overstate
// blockers (delay a win, never fabricate one). Commit protocol: re-read
// neighbor winC AFTER the scan reads (per-wave DS FIFO orders them);
// publisher writes winC BEFORE zeroing its scans. Zeroed scans seen by a
// reader always reflect a committed winner: if it covers om we abort, else
// the unblocking is exactly what true greedy would do. Ties: left blocks
// on >=, right on > == stable argsort(-|x|) order of the reference.
__global__ __launch_bounds__(NT) void extrema_nms_kernel(const float* __restrict__ in,
                                                         float* __restrict__ out) {
    __shared__ u32 pfxS[NC * SS];
    __shared__ u32 sfxS[NC * SS];
    __shared__ u32 TAc[NC];
    __shared__ u32 winC[NC];     // cumulative winner mask, one-hot, write-once

    const int tid = threadIdx.x;
    const int cc = tid + 2;
    const int base = tid * C;
    const float* xrow = in + (size_t)blockIdx.x * L;

    // ---- pads (written once, never again) ----
    if (tid < 4 * SS) {
        int rsel = tid / SS;
        int row = (rsel & 1) + ((rsel >> 1) ? (NT + 2) : 0);
        int col = tid % SS;
        pfxS[row * SS + col] = 0;
        sfxS[row * SS + col] = 0;
    }
    if (tid < 4) {
        int slot = (tid & 1) + ((tid >> 1) ? (NT + 2) : 0);
        TAc[slot] = 0;
        winC[slot] = 0;
    }
    winC[cc] = 0;

    // ---- load own 16 x values + boundary neighbors ----
    float xv[C];
    #pragma unroll
    for (int k = 0; k < C; k += 4) {
        float4 f = *reinterpret_cast<const float4*>(xrow + base + k);
        xv[k] = f.x; xv[k + 1] = f.y; xv[k + 2] = f.z; xv[k + 3] = f.w;
    }
    float xl = (base > 0) ? xrow[base - 1] : 0.0f;
    float xr = (base + C < L) ? xrow[base + C] : 0.0f;

    // ---- extrema mask -> u32 keys ----
    // right[i] = (i<L-1) && x[i+1] >  x[i]; left[i] = (i==0) || x[i] <= x[i-1]
    u32 key[C];
    #pragma unroll
    for (int o = 0; o < C; ++o) {
        int i = base + o;
        float xi = xv[o];
        float xp = (o == 0) ? xl : xv[o - 1];
        float xn = (o == C - 1) ? xr : xv[o + 1];
        bool right = (i < L - 1) && (xn > xi);
        bool left  = (i == 0) || (xi <= xp);
        bool neg   = (xi <= 0.0f);
        bool ext = (right && left && neg) || (!right && !left && !neg);
        key[o] = ext ? ((__float_as_uint(xi) & 0x7fffffffu) + 1u) : 0u;
    }

    // ---- initial alive mask + scans ----
    u32 alivem = 0;
    #pragma unroll
    for (int o = 0; o < C; ++o) if (key[o]) alivem |= (1u << o);
    u32 run, om;
    RESCAN();
    u32 keptm = 0;
    __syncthreads();               // the only block barrier: init visibility

    // ---- barrier-free monotone peeling ----
    u64 appliedW0 = 0;
    u32 appliedW1 = 0;
    for (int it = 0; it < MAXIT; ++it) {
        if (__ballot(run != 0) == 0) break;    // wave-uniform exit
        CFENCE();                               // fresh LDS view this iteration
        if (run) {
            // batched reads: 4 winC + 4 scan scalars, one latency window
            u32 m0 = winC[cc - 2], m1 = winC[cc - 1];
            u32 m3 = winC[cc + 1], m4 = winC[cc + 2];
            u32 sL = sfxS[(cc - 2) * SS + (int)om];
            u32 tL = TAc[cc - 1], tR = TAc[cc + 1];
            u32 pR = pfxS[(cc + 2) * SS + (int)om];

            u64 W0 = (u64)m0 | ((u64)m1 << 16) | ((u64)m3 << 48);
            u32 W1 = m4;
            if (W0 != appliedW0 || W1 != appliedW1) {
                // ---- apply newly-seen winners ----
                appliedW0 = W0; appliedW1 = W1;
                u32 supmask; SUPMASK_OF(m0, m1, m3, m4, supmask);
                u32 nA = alivem & ~supmask;
                if (nA != alivem) {
                    alivem = nA;
                    if (nA == 0) {
                        ZERO_SCANS();
                        run = 0;
                    } else {
                        #pragma unroll
                        for (int o = 0; o < C; ++o)
                            key[o] = ((supmask >> o) & 1u) ? 0u : key[o];
                        RESCAN();
                        CFENCE();
                        // re-read scan operands at (possibly new) om
                        sL = sfxS[(cc - 2) * SS + (int)om];
                        tL = TAc[cc - 1]; tR = TAc[cc + 1];
                        pR = pfxS[(cc + 2) * SS + (int)om];
                    }
                }
            }
            // ---- detect: only the chunk's first argmax can win ----
            if (run) {
                u32 bL = umax(sL, tL);         // blocks iff >= run
                u32 bR = umax(tR, pR);         // blocks iff >  run
                if (bL < run && bR <= run) {
                    CFENCE();                  // re-reads issue AFTER scan reads
                    u32 n0 = winC[cc - 2], n1 = winC[cc - 1];
                    u32 n3 = winC[cc + 1], n4 = winC[cc + 2];
                    u32 sup2; SUPMASK_OF(n0, n1, n3, n4, sup2);
                    if (!((sup2 >> om) & 1u)) {
                        keptm |= 1u << om;
                        winC[cc] = 1u << om;   // publish winner FIRST...
                        CFENCE();              // ...then (per-wave DS FIFO) zeroes
                        ZERO_SCANS();          // own chunk fully dies
                        run = 0; alivem = 0;
                    }
                    // else: a new winner covers om; next iteration applies it
                }
            }
        }
    }

    // ---- output straight from registers (own region; no sync needed) ----
    float* orow = out + (size_t)blockIdx.x * L;
    #pragma unroll
    for (int k = 0; k < C; k += 4) {
        float4 f;
        f.x = ((keptm >> (k + 0)) & 1u) ? xv[k + 0] : 0.0f;
        f.y = ((keptm >> (k + 1)) & 1u) ? xv[k + 1] : 0.0f;
        f.z = ((keptm >> (k + 2)) & 1u) ? xv[k + 2] : 0.0f;
        f.w = ((keptm >> (k + 3)) & 1u) ? xv[k + 3] : 0.0f;
        *reinterpret_cast<float4*>(orow + base + k) = f;
    }
}

extern "C" void kernel_launch(void* const* d_in, const int* in_sizes, int n_in,
                              void* d_out, int out_size, void* d_ws, size_t ws_size,
                              hipStream_t stream) {
    const float* in = (const float*)d_in[0];
    float* out = (float*)d_out;
    int rows = in_sizes[0] / L;   // 128
    extrema_nms_kernel<<<rows, NT, 0, stream>>>(in, out);
}